// Round 9
// baseline (207.375 us; speedup 1.0000x reference)
//
#include <hip/hip_runtime.h>
#include <hip/hip_bf16.h>
#include <math.h>

#define TT   2048
#define KK   48
#define KP   68             // epilogue staging pitch in ushorts

typedef __attribute__((ext_vector_type(8))) short bf16x8;
typedef __attribute__((ext_vector_type(4))) float f32x4;
typedef __attribute__((ext_vector_type(2))) float f32x2;
typedef __attribute__((ext_vector_type(4))) unsigned int u32x4;
typedef unsigned short ushort_t;

union FragU { u32x4 u; bf16x8 h; };
union Q4   { f32x4 v; f32x2 h[2]; };

__device__ __forceinline__ float rlf(float x, int l) {
    return __uint_as_float((unsigned)__builtin_amdgcn_readlane((int)__float_as_uint(x), l));
}
// software pack (setup only)
__device__ __forceinline__ unsigned pk2(float a, float b) {
    __hip_bfloat162 h = __float22bfloat162_rn(make_float2(a, b));
    return *(unsigned*)&h;
}
// HW pack: single v_cvt_pk_bf16_f32 (RNE; gfx950-verified R7: -45us)
__device__ __forceinline__ unsigned pk2a(float a, float b) {
    unsigned r;
    asm("v_cvt_pk_bf16_f32 %0, %1, %2" : "=v"(r) : "v"(a), "v"(b));
    return r;
}
// packed fp32 mul (VOP3P, gfx90a+)
__device__ __forceinline__ f32x2 pkmul(f32x2 a, f32x2 b) {
    f32x2 d;
    asm("v_pk_mul_f32 %0, %1, %2" : "=v"(d) : "v"(a), "v"(b));
    return d;
}

// ---------------- Kernel 1: segment matrix products (register-resident Q) ----
// Templated on segment length: SEGT=64 doubles wave count (8/SIMD) to fill
// the per-step dependence-chain bubbles that 4 waves/SIMD couldn't (R8: 60%
// VALUBusy, grid-capped occupancy).
template <int SEGT, int NSEGT>
__global__ __launch_bounds__(64) void crf_seg_kernel(
    const float* __restrict__ logits,   // [B, T, K]
    const float* __restrict__ trans,    // [K, K]
    const int*   __restrict__ lens,     // [B]
    ushort_t*    __restrict__ Qout,     // [B*NSEGT][48*48] bf16 row-major
    float*       __restrict__ sigout)   // [B*NSEGT]
{
    constexpr int NFULLT = NSEGT - 1;
    const int b    = blockIdx.x;
    const int seg  = blockIdx.y;        // 0..NSEGT-1
    const int job  = b * NSEGT + seg;
    const int lane = threadIdx.x;
    const int c = lane & 15, g = lane >> 4;

    int t0, t1;
    if (seg < NFULLT) { t0 = SEGT * seg + 1; t1 = SEGT * seg + SEGT; }
    else {
        int L  = lens[b];
        int nf = (L >= 2) ? (L - 1) / SEGT : 0;
        if (nf > NFULLT) nf = NFULLT;
        t0 = SEGT * nf + 1; t1 = L - 1;   // may be empty (t1 < t0) -> Q = I
    }

    __shared__ float    eLs[2][64];
    __shared__ ushort_t Qst[KK * KP];    // epilogue staging only

    // Constant A fragments: A[mt][q], row r = 16mt + c, k per bijection.
    FragU A[3][2];
    #pragma unroll
    for (int mt = 0; mt < 3; ++mt) {
        const int r = 16 * mt + c;
        #pragma unroll
        for (int q = 0; q < 2; ++q) {
            #pragma unroll
            for (int ep = 0; ep < 4; ++ep) {
                float v0, v1;
                { int e = 2 * ep;     int kk = 32 * q + 16 * (e >> 2) + 4 * g + (e & 3);
                  v0 = (kk < KK) ? __expf(trans[kk * KK + r]) : 0.f; }
                { int e = 2 * ep + 1; int kk = 32 * q + 16 * (e >> 2) + 4 * g + (e & 3);
                  v1 = (kk < KK) ? __expf(trans[kk * KK + r]) : 0.f; }
                A[mt][q].u[ep] = pk2(v0, v1);
            }
        }
    }

    // Bf init = identity columns: elem (q,e) of tile nt = I[k][16nt+c].
    FragU Bf[3][2];
    #pragma unroll
    for (int nt = 0; nt < 3; ++nt) {
        const int n = 16 * nt + c;
        #pragma unroll
        for (int q = 0; q < 2; ++q) {
            #pragma unroll
            for (int ep = 0; ep < 4; ++ep) {
                int e0 = 2 * ep, e1 = 2 * ep + 1;
                int k0 = 32 * q + 16 * (e0 >> 2) + 4 * g + (e0 & 3);
                int k1 = 32 * q + 16 * (e1 >> 2) + 4 * g + (e1 & 3);
                unsigned lo = (k0 == n) ? 0x3F80u : 0u;
                unsigned hi = (k1 == n) ? 0x3F80u : 0u;
                Bf[nt][q].u[ep] = (hi << 16) | lo;
            }
        }
    }

    const float* lg_b = logits + (size_t)b * TT * KK;
    const int jj = (lane < KK) ? lane : 0;
    float sg = 0.f;
    const int nsteps = t1 - t0 + 1;

#define STEP(u_, G_)                                                          \
    {                                                                         \
        const int i = 8 * cs + (u_);                                          \
        f32x4 eL4[3];                                                         \
        _Pragma("unroll")                                                     \
        for (int mt = 0; mt < 3; ++mt)                                        \
            eL4[mt] = *(const f32x4*)&eLs[par][16 * mt + 4 * g];              \
        float lgn = pf[((u_) + 1) & 7];                                       \
        int nr = t0 + i + 9; if (nr > TT - 1) nr = TT - 1;                    \
        pf[((u_) + 1) & 7] = lg_b[nr * KK + jj];                              \
        if (lane < KK) eLs[par ^ 1][lane] = __expf(lgn);                      \
        f32x4 acc[3][3];                                                      \
        _Pragma("unroll")                                                     \
        for (int mt = 0; mt < 3; ++mt)                                        \
            _Pragma("unroll")                                                 \
            for (int nt = 0; nt < 3; ++nt) {                                  \
                f32x4 z = {0.f, 0.f, 0.f, 0.f};                               \
                f32x4 a1 = __builtin_amdgcn_mfma_f32_16x16x32_bf16(           \
                               A[mt][0].h, Bf[nt][0].h, z, 0, 0, 0);          \
                acc[mt][nt] = __builtin_amdgcn_mfma_f32_16x16x32_bf16(        \
                               A[mt][1].h, Bf[nt][1].h, a1, 0, 0, 0);         \
            }                                                                 \
        float r = __uint_as_float((unsigned)__builtin_amdgcn_readfirstlane(   \
                      (int)__float_as_uint(acc[0][0][0])));                   \
        float rr = __builtin_amdgcn_rcpf(r);                                  \
        float logr = __logf(r);                                               \
        bool jk = G_ ? (i >= nsteps) : false;                                 \
        sg += jk ? 0.f : logr;                                                \
        f32x2 rr2 = {rr, rr};                                                 \
        Q4 es0, es1, es2;                                                     \
        { Q4 e0_; e0_.v = eL4[0]; es0.h[0] = pkmul(e0_.h[0], rr2);            \
                                  es0.h[1] = pkmul(e0_.h[1], rr2); }          \
        { Q4 e1_; e1_.v = eL4[1]; es1.h[0] = pkmul(e1_.h[0], rr2);            \
                                  es1.h[1] = pkmul(e1_.h[1], rr2); }          \
        { Q4 e2_; e2_.v = eL4[2]; es2.h[0] = pkmul(e2_.h[0], rr2);            \
                                  es2.h[1] = pkmul(e2_.h[1], rr2); }          \
        _Pragma("unroll")                                                     \
        for (int nt = 0; nt < 3; ++nt) {                                      \
            Q4 a0_, a1_, a2_;                                                 \
            a0_.v = acc[0][nt]; a1_.v = acc[1][nt]; a2_.v = acc[2][nt];       \
            f32x2 v00 = pkmul(a0_.h[0], es0.h[0]);                            \
            f32x2 v01 = pkmul(a0_.h[1], es0.h[1]);                            \
            f32x2 v10 = pkmul(a1_.h[0], es1.h[0]);                            \
            f32x2 v11 = pkmul(a1_.h[1], es1.h[1]);                            \
            f32x2 v20 = pkmul(a2_.h[0], es2.h[0]);                            \
            f32x2 v21 = pkmul(a2_.h[1], es2.h[1]);                            \
            unsigned w0 = pk2a(v00[0], v00[1]);                               \
            unsigned w1 = pk2a(v01[0], v01[1]);                               \
            unsigned w2 = pk2a(v10[0], v10[1]);                               \
            unsigned w3 = pk2a(v11[0], v11[1]);                               \
            unsigned w4 = pk2a(v20[0], v20[1]);                               \
            unsigned w5 = pk2a(v21[0], v21[1]);                               \
            if (G_) {                                                         \
                Bf[nt][0].u[0] = jk ? Bf[nt][0].u[0] : w0;                    \
                Bf[nt][0].u[1] = jk ? Bf[nt][0].u[1] : w1;                    \
                Bf[nt][0].u[2] = jk ? Bf[nt][0].u[2] : w2;                    \
                Bf[nt][0].u[3] = jk ? Bf[nt][0].u[3] : w3;                    \
                Bf[nt][1].u[0] = jk ? Bf[nt][1].u[0] : w4;                    \
                Bf[nt][1].u[1] = jk ? Bf[nt][1].u[1] : w5;                    \
            } else {                                                          \
                Bf[nt][0].u[0] = w0; Bf[nt][0].u[1] = w1;                     \
                Bf[nt][0].u[2] = w2; Bf[nt][0].u[3] = w3;                     \
                Bf[nt][1].u[0] = w4; Bf[nt][1].u[1] = w5;                     \
            }                                                                 \
            Bf[nt][1].u[2] = 0u; Bf[nt][1].u[3] = 0u;                         \
        }                                                                     \
        par ^= 1;                                                             \
    }

    int par = 0;
    if (nsteps > 0) {
        if (lane < KK) eLs[0][lane] = __expf(lg_b[t0 * KK + jj]);
        float pf[8];
        #pragma unroll
        for (int j = 1; j < 8; ++j) {
            int rj = t0 + j; if (rj > TT - 1) rj = TT - 1;
            pf[j] = lg_b[rj * KK + jj];
        }
        { int rj = t0 + 8; if (rj > TT - 1) rj = TT - 1; pf[0] = lg_b[rj * KK + jj]; }

        const int nchunks = (nsteps + 7) / 8;
        #pragma unroll 1
        for (int cs = 0; cs < nchunks - 1; ++cs) {
            STEP(0, false) STEP(1, false) STEP(2, false) STEP(3, false)
            STEP(4, false) STEP(5, false) STEP(6, false) STEP(7, false)
        }
        {   // last chunk: junk-guarded (freezes Bf/sg for i >= nsteps)
            const int cs = nchunks - 1;
            STEP(0, true) STEP(1, true) STEP(2, true) STEP(3, true)
            STEP(4, true) STEP(5, true) STEP(6, true) STEP(7, true)
        }
    }
#undef STEP

    // ---- epilogue: stage Bf (= final Q, bf16) to LDS, then linear store ----
    #pragma unroll
    for (int nt = 0; nt < 3; ++nt) {
        ushort_t* basep = &Qst[(16 * nt + c) * KP];
        *(unsigned*)&basep[4 * g]          = Bf[nt][0].u[0];
        *(unsigned*)&basep[4 * g + 2]      = Bf[nt][0].u[1];
        *(unsigned*)&basep[16 + 4 * g]     = Bf[nt][0].u[2];
        *(unsigned*)&basep[16 + 4 * g + 2] = Bf[nt][0].u[3];
        *(unsigned*)&basep[32 + 4 * g]     = Bf[nt][1].u[0];
        *(unsigned*)&basep[32 + 4 * g + 2] = Bf[nt][1].u[1];
    }
    __syncthreads();

    if (lane < KK) {
        const int m = lane;
        unsigned w[24];
        #pragma unroll
        for (int np = 0; np < 24; ++np) {
            unsigned lo = Qst[(2 * np)     * KP + m];
            unsigned hi = Qst[(2 * np + 1) * KP + m];
            w[np] = (hi << 16) | lo;
        }
        ushort_t* dst = Qout + (size_t)job * (KK * KK) + m * KK;
        #pragma unroll
        for (int i4 = 0; i4 < 6; ++i4) {
            uint4 o; o.x = w[4*i4]; o.y = w[4*i4+1]; o.z = w[4*i4+2]; o.w = w[4*i4+3];
            *(uint4*)&dst[8 * i4] = o;
        }
    }
    if (lane == 0) sigout[job] = sg;
}

// ---------------- Kernel 2: per-batch combine + scores ----------------
template <int SEGT, int NSEGT>
__global__ __launch_bounds__(64) void crf_comb_kernel(
    const float* __restrict__ logits, const float* __restrict__ trans,
    const int* __restrict__ targets, const int* __restrict__ lens,
    const ushort_t* __restrict__ Qall, const float* __restrict__ sig,
    float* __restrict__ out)
{
    constexpr int NFULLT = NSEGT - 1;
    const int b = blockIdx.x, lane = threadIdx.x;
    const int jj = (lane < KK) ? lane : 0;
    const int L = lens[b];

    __shared__ float s_trans[KK * KK];
    for (int k = lane; k < KK * KK; k += 64) s_trans[k] = trans[k];
    __syncthreads();

    const float* lg_b = logits  + (size_t)b * TT * KK;
    const int*   tg_b = targets + (size_t)b * TT;

    float ub = 0.f;
    #pragma unroll 4
    for (int t = lane; t < TT; t += 64) {
        if (t < L) {
            int tg = tg_b[t];
            ub += lg_b[t * KK + tg];
            if (t >= 1) { int tp = tg_b[t - 1]; ub += s_trans[tp * KK + tg]; }
        }
    }
    #pragma unroll
    for (int d = 32; d >= 1; d >>= 1) ub += __shfl_xor(ub, d, 64);

    float log_norm = 0.f;
    if (L > 0) {
        float a0 = lg_b[jj];
        float M  = rlf(a0, 0);
        float s  = (lane < KK) ? __expf(a0 - M) : 0.f;
        int nf = (L >= 2) ? (L - 1) / SEGT : 0;
        if (nf > NFULLT) nf = NFULLT;

        for (int ci = 0; ci <= nf; ++ci) {           // full segments, then tail
            const int job = b * NSEGT + ((ci < nf) ? ci : NFULLT);
            const ushort_t* Qr = Qall + (size_t)job * (KK * KK) + jj * KK;
            unsigned rw[24];
            #pragma unroll
            for (int i4 = 0; i4 < 6; ++i4) {
                uint4 v = *(const uint4*)&Qr[8 * i4];
                rw[4*i4] = v.x; rw[4*i4+1] = v.y; rw[4*i4+2] = v.z; rw[4*i4+3] = v.w;
            }
            float acc = 0.f;
            #pragma unroll
            for (int ip = 0; ip < 24; ++ip) {
                unsigned u = rw[ip];
                float q0 = __uint_as_float(u << 16);
                float q1 = __uint_as_float(u & 0xFFFF0000u);
                acc = fmaf(rlf(s, 2 * ip),     q0, acc);
                acc = fmaf(rlf(s, 2 * ip + 1), q1, acc);
            }
            float r  = rlf(acc, 0);
            float rr = __builtin_amdgcn_rcpf(r);
            s = (lane < KK) ? acc * rr : 0.f;
            M += __logf(r) + sig[job];
        }

        float ssum = (lane < KK) ? s : 0.f;
        #pragma unroll
        for (int d = 32; d >= 1; d >>= 1) ssum += __shfl_xor(ssum, d, 64);
        log_norm = M + __logf(ssum);
    }

    if (lane == 0) out[b] = (L <= 0) ? 0.f : (ub - log_norm);
}

// ---------------- Round-3 fallback (ws too small) ----------------
__global__ __launch_bounds__(64) void crf_fwd_fallback(
    const float* __restrict__ logits, const float* __restrict__ trans,
    const int* __restrict__ targets, const int* __restrict__ lens,
    float* __restrict__ out)
{
    const int b = blockIdx.x, lane = threadIdx.x;
    const int jj = (lane < KK) ? lane : 0;
    const int L = lens[b];
    __shared__ float s_trans[KK * KK];
    for (int k = lane; k < KK * KK; k += 64) s_trans[k] = trans[k];
    float et[KK];
    #pragma unroll
    for (int i = 0; i < KK; ++i) et[i] = __expf(trans[i * KK + jj]);
    __syncthreads();
    const float* lg_b = logits + (size_t)b * TT * KK;
    const int* tg_b = targets + (size_t)b * TT;
    float ub = 0.f;
    for (int t = lane; t < TT; t += 64) {
        if (t < L) {
            int tg = tg_b[t];
            ub += lg_b[t * KK + tg];
            if (t >= 1) { int tp = tg_b[t - 1]; ub += s_trans[tp * KK + tg]; }
        }
    }
    #pragma unroll
    for (int d = 32; d >= 1; d >>= 1) ub += __shfl_xor(ub, d, 64);
    float a0 = lg_b[jj];
    float M = rlf(a0, 0);
    float s = (lane < KK) ? __expf(a0 - M) : 0.f;
    float sC = s, MC = M;
    const int Lm1 = L - 1;
    float pf[8];
    #pragma unroll
    for (int u = 0; u < 8; ++u) pf[u] = lg_b[(1 + u) * KK + jj];
    #pragma unroll 1
    for (int cc = 0; cc < 256; ++cc) {
        #pragma unroll
        for (int u = 0; u < 8; ++u) {
            const int t = 1 + cc * 8 + u;
            float lg = pf[u];
            int nrow = t + 8; if (nrow > TT - 1) nrow = TT - 1;
            pf[u] = lg_b[nrow * KK + jj];
            float eL = __expf(lg);
            float ac0 = 0.f, ac1 = 0.f, ac2 = 0.f, ac3 = 0.f;
            #pragma unroll
            for (int i = 0; i < KK; i += 4) {
                float s0 = rlf(s, i), s1 = rlf(s, i+1), s2 = rlf(s, i+2), s3 = rlf(s, i+3);
                ac0 = fmaf(s0, et[i], ac0);   ac1 = fmaf(s1, et[i+1], ac1);
                ac2 = fmaf(s2, et[i+2], ac2); ac3 = fmaf(s3, et[i+3], ac3);
            }
            float e = ((ac0 + ac1) + (ac2 + ac3)) * eL;
            bool cap = (t == Lm1);
            sC = cap ? e : sC;  MC = cap ? M : MC;
            float r = rlf(e, 0);
            s = e * __builtin_amdgcn_rcpf(r);
            M += __logf(r);
        }
    }
    float ssum = (lane < KK) ? sC : 0.f;
    #pragma unroll
    for (int d = 32; d >= 1; d >>= 1) ssum += __shfl_xor(ssum, d, 64);
    float log_norm = MC + __logf(ssum);
    if (lane == 0) out[b] = (L <= 0) ? 0.f : (ub - log_norm);
}

extern "C" void kernel_launch(void* const* d_in, const int* in_sizes, int n_in,
                              void* d_out, int out_size, void* d_ws, size_t ws_size,
                              hipStream_t stream) {
    const float* logits  = (const float*)d_in[0];
    const float* trans   = (const float*)d_in[1];
    const int*   targets = (const int*)  d_in[2];
    const int*   lens    = (const int*)  d_in[3];
    float*       out     = (float*)d_out;
    const int B = in_sizes[3];

    const size_t q64  = (size_t)B * 32 * KK * KK * sizeof(ushort_t);
    const size_t n64  = q64 + (size_t)B * 32 * sizeof(float);
    const size_t q128 = (size_t)B * 16 * KK * KK * sizeof(ushort_t);
    const size_t n128 = q128 + (size_t)B * 16 * sizeof(float);

    if (ws_size >= n64) {
        ushort_t* Qout = (ushort_t*)d_ws;
        float*    sig  = (float*)((char*)d_ws + q64);
        crf_seg_kernel<64, 32><<<dim3(B, 32), 64, 0, stream>>>(logits, trans, lens, Qout, sig);
        crf_comb_kernel<64, 32><<<B, 64, 0, stream>>>(logits, trans, targets, lens, Qout, sig, out);
    } else if (ws_size >= n128) {
        ushort_t* Qout = (ushort_t*)d_ws;
        float*    sig  = (float*)((char*)d_ws + q128);
        crf_seg_kernel<128, 16><<<dim3(B, 16), 64, 0, stream>>>(logits, trans, lens, Qout, sig);
        crf_comb_kernel<128, 16><<<B, 64, 0, stream>>>(logits, trans, targets, lens, Qout, sig, out);
    } else {
        crf_fwd_fallback<<<B, 64, 0, stream>>>(logits, trans, targets, lens, out);
    }
}

// Round 10
// 193.200 us; speedup vs baseline: 1.0734x; 1.0734x over previous
//
#include <hip/hip_runtime.h>
#include <hip/hip_bf16.h>
#include <math.h>

#define TT   2048
#define KK   48
#define KP   68             // epilogue staging pitch in ushorts

typedef __attribute__((ext_vector_type(8))) short bf16x8;
typedef __attribute__((ext_vector_type(4))) float f32x4;
typedef __attribute__((ext_vector_type(2))) float f32x2;
typedef __attribute__((ext_vector_type(4))) unsigned int u32x4;
typedef unsigned short ushort_t;

union FragU { u32x4 u; bf16x8 h; };
union Q4   { f32x4 v; f32x2 h[2]; };

__device__ __forceinline__ float rlf(float x, int l) {
    return __uint_as_float((unsigned)__builtin_amdgcn_readlane((int)__float_as_uint(x), l));
}
// software pack (setup only)
__device__ __forceinline__ unsigned pk2(float a, float b) {
    __hip_bfloat162 h = __float22bfloat162_rn(make_float2(a, b));
    return *(unsigned*)&h;
}
// HW pack: single v_cvt_pk_bf16_f32 (RNE; gfx950-verified R7: -45us)
__device__ __forceinline__ unsigned pk2a(float a, float b) {
    unsigned r;
    asm("v_cvt_pk_bf16_f32 %0, %1, %2" : "=v"(r) : "v"(a), "v"(b));
    return r;
}
// packed fp32 mul (VOP3P, gfx90a+)
__device__ __forceinline__ f32x2 pkmul(f32x2 a, f32x2 b) {
    f32x2 d;
    asm("v_pk_mul_f32 %0, %1, %2" : "=v"(d) : "v"(a), "v"(b));
    return d;
}

// ---------------- Kernel 1: segment matrix products (register-resident Q) ----
// R10: __launch_bounds__(64,4) caps unified VGPR+AGPR at 128/wave -> 4
// waves/SIMD (R9 showed occupancy is register-capped at ~2.3/SIMD by the
// AGPR split, not grid-capped). Persistent pinned zero kills per-step C-init
// materialization.
template <int SEGT, int NSEGT>
__global__ __launch_bounds__(64, 4) void crf_seg_kernel(
    const float* __restrict__ logits,   // [B, T, K]
    const float* __restrict__ trans,    // [K, K]
    const int*   __restrict__ lens,     // [B]
    ushort_t*    __restrict__ Qout,     // [B*NSEGT][48*48] bf16 row-major
    float*       __restrict__ sigout)   // [B*NSEGT]
{
    constexpr int NFULLT = NSEGT - 1;
    const int b    = blockIdx.x;
    const int seg  = blockIdx.y;        // 0..NSEGT-1
    const int job  = b * NSEGT + seg;
    const int lane = threadIdx.x;
    const int c = lane & 15, g = lane >> 4;

    int t0, t1;
    if (seg < NFULLT) { t0 = SEGT * seg + 1; t1 = SEGT * seg + SEGT; }
    else {
        int L  = lens[b];
        int nf = (L >= 2) ? (L - 1) / SEGT : 0;
        if (nf > NFULLT) nf = NFULLT;
        t0 = SEGT * nf + 1; t1 = L - 1;   // may be empty (t1 < t0) -> Q = I
    }

    __shared__ float    eLs[2][64];
    __shared__ ushort_t Qst[KK * KP];    // epilogue staging only

    // Constant A fragments: A[mt][q], row r = 16mt + c, k per bijection.
    FragU A[3][2];
    #pragma unroll
    for (int mt = 0; mt < 3; ++mt) {
        const int r = 16 * mt + c;
        #pragma unroll
        for (int q = 0; q < 2; ++q) {
            #pragma unroll
            for (int ep = 0; ep < 4; ++ep) {
                float v0, v1;
                { int e = 2 * ep;     int kk = 32 * q + 16 * (e >> 2) + 4 * g + (e & 3);
                  v0 = (kk < KK) ? __expf(trans[kk * KK + r]) : 0.f; }
                { int e = 2 * ep + 1; int kk = 32 * q + 16 * (e >> 2) + 4 * g + (e & 3);
                  v1 = (kk < KK) ? __expf(trans[kk * KK + r]) : 0.f; }
                A[mt][q].u[ep] = pk2(v0, v1);
            }
        }
    }

    // Bf init = identity columns: elem (q,e) of tile nt = I[k][16nt+c].
    FragU Bf[3][2];
    #pragma unroll
    for (int nt = 0; nt < 3; ++nt) {
        const int n = 16 * nt + c;
        #pragma unroll
        for (int q = 0; q < 2; ++q) {
            #pragma unroll
            for (int ep = 0; ep < 4; ++ep) {
                int e0 = 2 * ep, e1 = 2 * ep + 1;
                int k0 = 32 * q + 16 * (e0 >> 2) + 4 * g + (e0 & 3);
                int k1 = 32 * q + 16 * (e1 >> 2) + 4 * g + (e1 & 3);
                unsigned lo = (k0 == n) ? 0x3F80u : 0u;
                unsigned hi = (k1 == n) ? 0x3F80u : 0u;
                Bf[nt][q].u[ep] = (hi << 16) | lo;
            }
        }
    }

    const float* lg_b = logits + (size_t)b * TT * KK;
    const int jj = (lane < KK) ? lane : 0;
    float sg = 0.f;
    const int nsteps = t1 - t0 + 1;

    // Persistent zero C-init (pinned so it isn't re-materialized per MFMA)
    f32x4 z4 = {0.f, 0.f, 0.f, 0.f};
    asm("" : "+v"(z4));

#define STEP(u_, G_)                                                          \
    {                                                                         \
        const int i = 8 * cs + (u_);                                          \
        f32x4 eL4[3];                                                         \
        _Pragma("unroll")                                                     \
        for (int mt = 0; mt < 3; ++mt)                                        \
            eL4[mt] = *(const f32x4*)&eLs[par][16 * mt + 4 * g];              \
        float lgn = pf[((u_) + 1) & 7];                                       \
        int nr = t0 + i + 9; if (nr > TT - 1) nr = TT - 1;                    \
        pf[((u_) + 1) & 7] = lg_b[nr * KK + jj];                              \
        if (lane < KK) eLs[par ^ 1][lane] = __expf(lgn);                      \
        f32x4 acc[3][3];                                                      \
        _Pragma("unroll")                                                     \
        for (int mt = 0; mt < 3; ++mt)                                        \
            _Pragma("unroll")                                                 \
            for (int nt = 0; nt < 3; ++nt) {                                  \
                f32x4 a1 = __builtin_amdgcn_mfma_f32_16x16x32_bf16(           \
                               A[mt][0].h, Bf[nt][0].h, z4, 0, 0, 0);         \
                acc[mt][nt] = __builtin_amdgcn_mfma_f32_16x16x32_bf16(        \
                               A[mt][1].h, Bf[nt][1].h, a1, 0, 0, 0);         \
            }                                                                 \
        float r = __uint_as_float((unsigned)__builtin_amdgcn_readfirstlane(   \
                      (int)__float_as_uint(acc[0][0][0])));                   \
        float rr = __builtin_amdgcn_rcpf(r);                                  \
        float logr = __logf(r);                                               \
        bool jk = G_ ? (i >= nsteps) : false;                                 \
        sg += jk ? 0.f : logr;                                                \
        f32x2 rr2 = {rr, rr};                                                 \
        Q4 es0, es1, es2;                                                     \
        { Q4 e0_; e0_.v = eL4[0]; es0.h[0] = pkmul(e0_.h[0], rr2);            \
                                  es0.h[1] = pkmul(e0_.h[1], rr2); }          \
        { Q4 e1_; e1_.v = eL4[1]; es1.h[0] = pkmul(e1_.h[0], rr2);            \
                                  es1.h[1] = pkmul(e1_.h[1], rr2); }          \
        { Q4 e2_; e2_.v = eL4[2]; es2.h[0] = pkmul(e2_.h[0], rr2);            \
                                  es2.h[1] = pkmul(e2_.h[1], rr2); }          \
        _Pragma("unroll")                                                     \
        for (int nt = 0; nt < 3; ++nt) {                                      \
            Q4 a0_, a1_, a2_;                                                 \
            a0_.v = acc[0][nt]; a1_.v = acc[1][nt]; a2_.v = acc[2][nt];       \
            f32x2 v00 = pkmul(a0_.h[0], es0.h[0]);                            \
            f32x2 v01 = pkmul(a0_.h[1], es0.h[1]);                            \
            f32x2 v10 = pkmul(a1_.h[0], es1.h[0]);                            \
            f32x2 v11 = pkmul(a1_.h[1], es1.h[1]);                            \
            f32x2 v20 = pkmul(a2_.h[0], es2.h[0]);                            \
            f32x2 v21 = pkmul(a2_.h[1], es2.h[1]);                            \
            unsigned w0 = pk2a(v00[0], v00[1]);                               \
            unsigned w1 = pk2a(v01[0], v01[1]);                               \
            unsigned w2 = pk2a(v10[0], v10[1]);                               \
            unsigned w3 = pk2a(v11[0], v11[1]);                               \
            unsigned w4 = pk2a(v20[0], v20[1]);                               \
            unsigned w5 = pk2a(v21[0], v21[1]);                               \
            if (G_) {                                                         \
                Bf[nt][0].u[0] = jk ? Bf[nt][0].u[0] : w0;                    \
                Bf[nt][0].u[1] = jk ? Bf[nt][0].u[1] : w1;                    \
                Bf[nt][0].u[2] = jk ? Bf[nt][0].u[2] : w2;                    \
                Bf[nt][0].u[3] = jk ? Bf[nt][0].u[3] : w3;                    \
                Bf[nt][1].u[0] = jk ? Bf[nt][1].u[0] : w4;                    \
                Bf[nt][1].u[1] = jk ? Bf[nt][1].u[1] : w5;                    \
            } else {                                                          \
                Bf[nt][0].u[0] = w0; Bf[nt][0].u[1] = w1;                     \
                Bf[nt][0].u[2] = w2; Bf[nt][0].u[3] = w3;                     \
                Bf[nt][1].u[0] = w4; Bf[nt][1].u[1] = w5;                     \
            }                                                                 \
            Bf[nt][1].u[2] = 0u; Bf[nt][1].u[3] = 0u;                         \
        }                                                                     \
        par ^= 1;                                                             \
    }

    int par = 0;
    if (nsteps > 0) {
        if (lane < KK) eLs[0][lane] = __expf(lg_b[t0 * KK + jj]);
        float pf[8];
        #pragma unroll
        for (int j = 1; j < 8; ++j) {
            int rj = t0 + j; if (rj > TT - 1) rj = TT - 1;
            pf[j] = lg_b[rj * KK + jj];
        }
        { int rj = t0 + 8; if (rj > TT - 1) rj = TT - 1; pf[0] = lg_b[rj * KK + jj]; }

        const int nchunks = (nsteps + 7) / 8;
        #pragma unroll 1
        for (int cs = 0; cs < nchunks - 1; ++cs) {
            STEP(0, false) STEP(1, false) STEP(2, false) STEP(3, false)
            STEP(4, false) STEP(5, false) STEP(6, false) STEP(7, false)
        }
        {   // last chunk: junk-guarded (freezes Bf/sg for i >= nsteps)
            const int cs = nchunks - 1;
            STEP(0, true) STEP(1, true) STEP(2, true) STEP(3, true)
            STEP(4, true) STEP(5, true) STEP(6, true) STEP(7, true)
        }
    }
#undef STEP

    // ---- epilogue: stage Bf (= final Q, bf16) to LDS, then linear store ----
    #pragma unroll
    for (int nt = 0; nt < 3; ++nt) {
        ushort_t* basep = &Qst[(16 * nt + c) * KP];
        *(unsigned*)&basep[4 * g]          = Bf[nt][0].u[0];
        *(unsigned*)&basep[4 * g + 2]      = Bf[nt][0].u[1];
        *(unsigned*)&basep[16 + 4 * g]     = Bf[nt][0].u[2];
        *(unsigned*)&basep[16 + 4 * g + 2] = Bf[nt][0].u[3];
        *(unsigned*)&basep[32 + 4 * g]     = Bf[nt][1].u[0];
        *(unsigned*)&basep[32 + 4 * g + 2] = Bf[nt][1].u[1];
    }
    __syncthreads();

    if (lane < KK) {
        const int m = lane;
        unsigned w[24];
        #pragma unroll
        for (int np = 0; np < 24; ++np) {
            unsigned lo = Qst[(2 * np)     * KP + m];
            unsigned hi = Qst[(2 * np + 1) * KP + m];
            w[np] = (hi << 16) | lo;
        }
        ushort_t* dst = Qout + (size_t)job * (KK * KK) + m * KK;
        #pragma unroll
        for (int i4 = 0; i4 < 6; ++i4) {
            uint4 o; o.x = w[4*i4]; o.y = w[4*i4+1]; o.z = w[4*i4+2]; o.w = w[4*i4+3];
            *(uint4*)&dst[8 * i4] = o;
        }
    }
    if (lane == 0) sigout[job] = sg;
}

// ---------------- Kernel 2: per-batch combine + scores ----------------
template <int SEGT, int NSEGT>
__global__ __launch_bounds__(64) void crf_comb_kernel(
    const float* __restrict__ logits, const float* __restrict__ trans,
    const int* __restrict__ targets, const int* __restrict__ lens,
    const ushort_t* __restrict__ Qall, const float* __restrict__ sig,
    float* __restrict__ out)
{
    constexpr int NFULLT = NSEGT - 1;
    const int b = blockIdx.x, lane = threadIdx.x;
    const int jj = (lane < KK) ? lane : 0;
    const int L = lens[b];

    __shared__ float s_trans[KK * KK];
    for (int k = lane; k < KK * KK; k += 64) s_trans[k] = trans[k];
    __syncthreads();

    const float* lg_b = logits  + (size_t)b * TT * KK;
    const int*   tg_b = targets + (size_t)b * TT;

    float ub = 0.f;
    #pragma unroll 4
    for (int t = lane; t < TT; t += 64) {
        if (t < L) {
            int tg = tg_b[t];
            ub += lg_b[t * KK + tg];
            if (t >= 1) { int tp = tg_b[t - 1]; ub += s_trans[tp * KK + tg]; }
        }
    }
    #pragma unroll
    for (int d = 32; d >= 1; d >>= 1) ub += __shfl_xor(ub, d, 64);

    float log_norm = 0.f;
    if (L > 0) {
        float a0 = lg_b[jj];
        float M  = rlf(a0, 0);
        float s  = (lane < KK) ? __expf(a0 - M) : 0.f;
        int nf = (L >= 2) ? (L - 1) / SEGT : 0;
        if (nf > NFULLT) nf = NFULLT;

        for (int ci = 0; ci <= nf; ++ci) {           // full segments, then tail
            const int job = b * NSEGT + ((ci < nf) ? ci : NFULLT);
            const ushort_t* Qr = Qall + (size_t)job * (KK * KK) + jj * KK;
            unsigned rw[24];
            #pragma unroll
            for (int i4 = 0; i4 < 6; ++i4) {
                uint4 v = *(const uint4*)&Qr[8 * i4];
                rw[4*i4] = v.x; rw[4*i4+1] = v.y; rw[4*i4+2] = v.z; rw[4*i4+3] = v.w;
            }
            float acc = 0.f;
            #pragma unroll
            for (int ip = 0; ip < 24; ++ip) {
                unsigned u = rw[ip];
                float q0 = __uint_as_float(u << 16);
                float q1 = __uint_as_float(u & 0xFFFF0000u);
                acc = fmaf(rlf(s, 2 * ip),     q0, acc);
                acc = fmaf(rlf(s, 2 * ip + 1), q1, acc);
            }
            float r  = rlf(acc, 0);
            float rr = __builtin_amdgcn_rcpf(r);
            s = (lane < KK) ? acc * rr : 0.f;
            M += __logf(r) + sig[job];
        }

        float ssum = (lane < KK) ? s : 0.f;
        #pragma unroll
        for (int d = 32; d >= 1; d >>= 1) ssum += __shfl_xor(ssum, d, 64);
        log_norm = M + __logf(ssum);
    }

    if (lane == 0) out[b] = (L <= 0) ? 0.f : (ub - log_norm);
}

// ---------------- Round-3 fallback (ws too small) ----------------
__global__ __launch_bounds__(64) void crf_fwd_fallback(
    const float* __restrict__ logits, const float* __restrict__ trans,
    const int* __restrict__ targets, const int* __restrict__ lens,
    float* __restrict__ out)
{
    const int b = blockIdx.x, lane = threadIdx.x;
    const int jj = (lane < KK) ? lane : 0;
    const int L = lens[b];
    __shared__ float s_trans[KK * KK];
    for (int k = lane; k < KK * KK; k += 64) s_trans[k] = trans[k];
    float et[KK];
    #pragma unroll
    for (int i = 0; i < KK; ++i) et[i] = __expf(trans[i * KK + jj]);
    __syncthreads();
    const float* lg_b = logits + (size_t)b * TT * KK;
    const int* tg_b = targets + (size_t)b * TT;
    float ub = 0.f;
    for (int t = lane; t < TT; t += 64) {
        if (t < L) {
            int tg = tg_b[t];
            ub += lg_b[t * KK + tg];
            if (t >= 1) { int tp = tg_b[t - 1]; ub += s_trans[tp * KK + tg]; }
        }
    }
    #pragma unroll
    for (int d = 32; d >= 1; d >>= 1) ub += __shfl_xor(ub, d, 64);
    float a0 = lg_b[jj];
    float M = rlf(a0, 0);
    float s = (lane < KK) ? __expf(a0 - M) : 0.f;
    float sC = s, MC = M;
    const int Lm1 = L - 1;
    float pf[8];
    #pragma unroll
    for (int u = 0; u < 8; ++u) pf[u] = lg_b[(1 + u) * KK + jj];
    #pragma unroll 1
    for (int cc = 0; cc < 256; ++cc) {
        #pragma unroll
        for (int u = 0; u < 8; ++u) {
            const int t = 1 + cc * 8 + u;
            float lg = pf[u];
            int nrow = t + 8; if (nrow > TT - 1) nrow = TT - 1;
            pf[u] = lg_b[nrow * KK + jj];
            float eL = __expf(lg);
            float ac0 = 0.f, ac1 = 0.f, ac2 = 0.f, ac3 = 0.f;
            #pragma unroll
            for (int i = 0; i < KK; i += 4) {
                float s0 = rlf(s, i), s1 = rlf(s, i+1), s2 = rlf(s, i+2), s3 = rlf(s, i+3);
                ac0 = fmaf(s0, et[i], ac0);   ac1 = fmaf(s1, et[i+1], ac1);
                ac2 = fmaf(s2, et[i+2], ac2); ac3 = fmaf(s3, et[i+3], ac3);
            }
            float e = ((ac0 + ac1) + (ac2 + ac3)) * eL;
            bool cap = (t == Lm1);
            sC = cap ? e : sC;  MC = cap ? M : MC;
            float r = rlf(e, 0);
            s = e * __builtin_amdgcn_rcpf(r);
            M += __logf(r);
        }
    }
    float ssum = (lane < KK) ? sC : 0.f;
    #pragma unroll
    for (int d = 32; d >= 1; d >>= 1) ssum += __shfl_xor(ssum, d, 64);
    float log_norm = MC + __logf(ssum);
    if (lane == 0) out[b] = (L <= 0) ? 0.f : (ub - log_norm);
}

extern "C" void kernel_launch(void* const* d_in, const int* in_sizes, int n_in,
                              void* d_out, int out_size, void* d_ws, size_t ws_size,
                              hipStream_t stream) {
    const float* logits  = (const float*)d_in[0];
    const float* trans   = (const float*)d_in[1];
    const int*   targets = (const int*)  d_in[2];
    const int*   lens    = (const int*)  d_in[3];
    float*       out     = (float*)d_out;
    const int B = in_sizes[3];

    const size_t q64  = (size_t)B * 32 * KK * KK * sizeof(ushort_t);
    const size_t n64  = q64 + (size_t)B * 32 * sizeof(float);
    const size_t q128 = (size_t)B * 16 * KK * KK * sizeof(ushort_t);
    const size_t n128 = q128 + (size_t)B * 16 * sizeof(float);

    if (ws_size >= n64) {
        ushort_t* Qout = (ushort_t*)d_ws;
        float*    sig  = (float*)((char*)d_ws + q64);
        crf_seg_kernel<64, 32><<<dim3(B, 32), 64, 0, stream>>>(logits, trans, lens, Qout, sig);
        crf_comb_kernel<64, 32><<<B, 64, 0, stream>>>(logits, trans, targets, lens, Qout, sig, out);
    } else if (ws_size >= n128) {
        ushort_t* Qout = (ushort_t*)d_ws;
        float*    sig  = (float*)((char*)d_ws + q128);
        crf_seg_kernel<128, 16><<<dim3(B, 16), 64, 0, stream>>>(logits, trans, lens, Qout, sig);
        crf_comb_kernel<128, 16><<<B, 64, 0, stream>>>(logits, trans, targets, lens, Qout, sig, out);
    } else {
        crf_fwd_fallback<<<B, 64, 0, stream>>>(logits, trans, targets, lens, out);
    }
}

// Round 11
// 187.936 us; speedup vs baseline: 1.1034x; 1.0280x over previous
//
#include <hip/hip_runtime.h>
#include <hip/hip_bf16.h>
#include <math.h>

#define TT   2048
#define KK   48
#define KP   68             // epilogue staging pitch in ushorts

typedef __attribute__((ext_vector_type(8))) short bf16x8;
typedef __attribute__((ext_vector_type(4))) float f32x4;
typedef __attribute__((ext_vector_type(2))) float f32x2;
typedef __attribute__((ext_vector_type(4))) unsigned int u32x4;
typedef unsigned short ushort_t;

union FragU { u32x4 u; bf16x8 h; };
union Q4   { f32x4 v; f32x2 h[2]; };

__device__ __forceinline__ float rlf(float x, int l) {
    return __uint_as_float((unsigned)__builtin_amdgcn_readlane((int)__float_as_uint(x), l));
}
// software pack (setup only)
__device__ __forceinline__ unsigned pk2(float a, float b) {
    __hip_bfloat162 h = __float22bfloat162_rn(make_float2(a, b));
    return *(unsigned*)&h;
}
// HW pack: single v_cvt_pk_bf16_f32 (RNE; gfx950-verified R7: -45us)
__device__ __forceinline__ unsigned pk2a(float a, float b) {
    unsigned r;
    asm("v_cvt_pk_bf16_f32 %0, %1, %2" : "=v"(r) : "v"(a), "v"(b));
    return r;
}
// packed fp32 mul (VOP3P, gfx90a+)
__device__ __forceinline__ f32x2 pkmul(f32x2 a, f32x2 b) {
    f32x2 d;
    asm("v_pk_mul_f32 %0, %1, %2" : "=v"(d) : "v"(a), "v"(b));
    return d;
}

// ---------------- Kernel 1: segment matrix products (register-resident Q) ----
// R11: column-serial step. R10 counters showed 425 VALU-cyc/step vs ~130
// static: acc[3][3] (36 regs) lived whole-step -> AGPR split -> accvgpr
// round-trips on every pkmul/cvt. Now each output column nt is computed
// (6 MFMA -> 12 regs) and repacked into Bf[nt] immediately, columns reuse the
// same 12 regs -> total live state ~100 regs, fits arch-VGPR budget.
template <int SEGT, int NSEGT>
__global__ __launch_bounds__(64, 4) void crf_seg_kernel(
    const float* __restrict__ logits,   // [B, T, K]
    const float* __restrict__ trans,    // [K, K]
    const int*   __restrict__ lens,     // [B]
    ushort_t*    __restrict__ Qout,     // [B*NSEGT][48*48] bf16 row-major
    float*       __restrict__ sigout)   // [B*NSEGT]
{
    constexpr int NFULLT = NSEGT - 1;
    const int b    = blockIdx.x;
    const int seg  = blockIdx.y;        // 0..NSEGT-1
    const int job  = b * NSEGT + seg;
    const int lane = threadIdx.x;
    const int c = lane & 15, g = lane >> 4;

    int t0, t1;
    if (seg < NFULLT) { t0 = SEGT * seg + 1; t1 = SEGT * seg + SEGT; }
    else {
        int L  = lens[b];
        int nf = (L >= 2) ? (L - 1) / SEGT : 0;
        if (nf > NFULLT) nf = NFULLT;
        t0 = SEGT * nf + 1; t1 = L - 1;   // may be empty (t1 < t0) -> Q = I
    }

    __shared__ float    eLs[2][64];
    __shared__ ushort_t Qst[KK * KP];    // epilogue staging only

    // Constant A fragments: A[mt][q], row r = 16mt + c, k per bijection.
    FragU A[3][2];
    #pragma unroll
    for (int mt = 0; mt < 3; ++mt) {
        const int r = 16 * mt + c;
        #pragma unroll
        for (int q = 0; q < 2; ++q) {
            #pragma unroll
            for (int ep = 0; ep < 4; ++ep) {
                float v0, v1;
                { int e = 2 * ep;     int kk = 32 * q + 16 * (e >> 2) + 4 * g + (e & 3);
                  v0 = (kk < KK) ? __expf(trans[kk * KK + r]) : 0.f; }
                { int e = 2 * ep + 1; int kk = 32 * q + 16 * (e >> 2) + 4 * g + (e & 3);
                  v1 = (kk < KK) ? __expf(trans[kk * KK + r]) : 0.f; }
                A[mt][q].u[ep] = pk2(v0, v1);
            }
        }
    }

    // Bf init = identity columns: elem (q,e) of tile nt = I[k][16nt+c].
    FragU Bf[3][2];
    #pragma unroll
    for (int nt = 0; nt < 3; ++nt) {
        const int n = 16 * nt + c;
        #pragma unroll
        for (int q = 0; q < 2; ++q) {
            #pragma unroll
            for (int ep = 0; ep < 4; ++ep) {
                int e0 = 2 * ep, e1 = 2 * ep + 1;
                int k0 = 32 * q + 16 * (e0 >> 2) + 4 * g + (e0 & 3);
                int k1 = 32 * q + 16 * (e1 >> 2) + 4 * g + (e1 & 3);
                unsigned lo = (k0 == n) ? 0x3F80u : 0u;
                unsigned hi = (k1 == n) ? 0x3F80u : 0u;
                Bf[nt][q].u[ep] = (hi << 16) | lo;
            }
        }
    }

    const float* lg_b = logits + (size_t)b * TT * KK;
    const int jj = (lane < KK) ? lane : 0;
    float sg = 0.f;
    const int nsteps = t1 - t0 + 1;

    // Persistent zero C-init (pinned so it isn't re-materialized per MFMA)
    f32x4 z4 = {0.f, 0.f, 0.f, 0.f};
    asm("" : "+v"(z4));

// One column: 6 MFMAs -> y0..y2 (12 regs), renorm extract on first column,
// immediate scale+repack into Bf[nt_]. y regs die here -> reused next column.
#define COLX(nt_, FIRST_)                                                     \
    {                                                                         \
        f32x4 y0 = __builtin_amdgcn_mfma_f32_16x16x32_bf16(                   \
                       A[0][0].h, Bf[nt_][0].h, z4, 0, 0, 0);                 \
        y0 = __builtin_amdgcn_mfma_f32_16x16x32_bf16(                         \
                       A[0][1].h, Bf[nt_][1].h, y0, 0, 0, 0);                 \
        f32x4 y1 = __builtin_amdgcn_mfma_f32_16x16x32_bf16(                   \
                       A[1][0].h, Bf[nt_][0].h, z4, 0, 0, 0);                 \
        y1 = __builtin_amdgcn_mfma_f32_16x16x32_bf16(                         \
                       A[1][1].h, Bf[nt_][1].h, y1, 0, 0, 0);                 \
        f32x4 y2 = __builtin_amdgcn_mfma_f32_16x16x32_bf16(                   \
                       A[2][0].h, Bf[nt_][0].h, z4, 0, 0, 0);                 \
        y2 = __builtin_amdgcn_mfma_f32_16x16x32_bf16(                         \
                       A[2][1].h, Bf[nt_][1].h, y2, 0, 0, 0);                 \
        if (FIRST_) {                                                         \
            float r = __uint_as_float((unsigned)                              \
                __builtin_amdgcn_readfirstlane((int)__float_as_uint(y0[0]))); \
            float rr = __builtin_amdgcn_rcpf(r);                              \
            sg += jk ? 0.f : __logf(r);                                       \
            rr2[0] = rr; rr2[1] = rr;                                         \
            { Q4 t_; t_.v = eL4[0]; es0.h[0] = pkmul(t_.h[0], rr2);           \
                                    es0.h[1] = pkmul(t_.h[1], rr2); }         \
            { Q4 t_; t_.v = eL4[1]; es1.h[0] = pkmul(t_.h[0], rr2);           \
                                    es1.h[1] = pkmul(t_.h[1], rr2); }         \
            { Q4 t_; t_.v = eL4[2]; es2.h[0] = pkmul(t_.h[0], rr2);           \
                                    es2.h[1] = pkmul(t_.h[1], rr2); }         \
        }                                                                     \
        Q4 q0_, q1_, q2_;                                                     \
        q0_.v = y0; q1_.v = y1; q2_.v = y2;                                   \
        f32x2 v00 = pkmul(q0_.h[0], es0.h[0]);                                \
        f32x2 v01 = pkmul(q0_.h[1], es0.h[1]);                                \
        f32x2 v10 = pkmul(q1_.h[0], es1.h[0]);                                \
        f32x2 v11 = pkmul(q1_.h[1], es1.h[1]);                                \
        f32x2 v20 = pkmul(q2_.h[0], es2.h[0]);                                \
        f32x2 v21 = pkmul(q2_.h[1], es2.h[1]);                                \
        unsigned w0 = pk2a(v00[0], v00[1]);                                   \
        unsigned w1 = pk2a(v01[0], v01[1]);                                   \
        unsigned w2 = pk2a(v10[0], v10[1]);                                   \
        unsigned w3 = pk2a(v11[0], v11[1]);                                   \
        unsigned w4 = pk2a(v20[0], v20[1]);                                   \
        unsigned w5 = pk2a(v21[0], v21[1]);                                   \
        if (G_) {                                                             \
            Bf[nt_][0].u[0] = jk ? Bf[nt_][0].u[0] : w0;                      \
            Bf[nt_][0].u[1] = jk ? Bf[nt_][0].u[1] : w1;                      \
            Bf[nt_][0].u[2] = jk ? Bf[nt_][0].u[2] : w2;                      \
            Bf[nt_][0].u[3] = jk ? Bf[nt_][0].u[3] : w3;                      \
            Bf[nt_][1].u[0] = jk ? Bf[nt_][1].u[0] : w4;                      \
            Bf[nt_][1].u[1] = jk ? Bf[nt_][1].u[1] : w5;                      \
        } else {                                                              \
            Bf[nt_][0].u[0] = w0; Bf[nt_][0].u[1] = w1;                       \
            Bf[nt_][0].u[2] = w2; Bf[nt_][0].u[3] = w3;                       \
            Bf[nt_][1].u[0] = w4; Bf[nt_][1].u[1] = w5;                       \
        }                                                                     \
        Bf[nt_][1].u[2] = 0u; Bf[nt_][1].u[3] = 0u;                           \
    }

#define STEP(u_, GG_)                                                         \
    {                                                                         \
        constexpr bool G_ = (GG_);                                            \
        const int i = 8 * cs + (u_);                                          \
        f32x4 eL4[3];                                                         \
        _Pragma("unroll")                                                     \
        for (int mt = 0; mt < 3; ++mt)                                        \
            eL4[mt] = *(const f32x4*)&eLs[par][16 * mt + 4 * g];              \
        float lgn = pf[((u_) + 1) & 7];                                       \
        int nr = t0 + i + 9; if (nr > TT - 1) nr = TT - 1;                    \
        pf[((u_) + 1) & 7] = lg_b[nr * KK + jj];                              \
        if (lane < KK) eLs[par ^ 1][lane] = __expf(lgn);                      \
        const bool jk = G_ ? (i >= nsteps) : false;                           \
        f32x2 rr2;                                                            \
        Q4 es0, es1, es2;                                                     \
        COLX(0, 1)                                                            \
        COLX(1, 0)                                                            \
        COLX(2, 0)                                                            \
        par ^= 1;                                                             \
    }

    int par = 0;
    if (nsteps > 0) {
        if (lane < KK) eLs[0][lane] = __expf(lg_b[t0 * KK + jj]);
        float pf[8];
        #pragma unroll
        for (int j = 1; j < 8; ++j) {
            int rj = t0 + j; if (rj > TT - 1) rj = TT - 1;
            pf[j] = lg_b[rj * KK + jj];
        }
        { int rj = t0 + 8; if (rj > TT - 1) rj = TT - 1; pf[0] = lg_b[rj * KK + jj]; }

        const int nchunks = (nsteps + 7) / 8;
        #pragma unroll 1
        for (int cs = 0; cs < nchunks - 1; ++cs) {
            STEP(0, false) STEP(1, false) STEP(2, false) STEP(3, false)
            STEP(4, false) STEP(5, false) STEP(6, false) STEP(7, false)
        }
        {   // last chunk: junk-guarded (freezes Bf/sg for i >= nsteps)
            const int cs = nchunks - 1;
            STEP(0, true) STEP(1, true) STEP(2, true) STEP(3, true)
            STEP(4, true) STEP(5, true) STEP(6, true) STEP(7, true)
        }
    }
#undef STEP
#undef COLX

    // ---- epilogue: stage Bf (= final Q, bf16) to LDS, then linear store ----
    #pragma unroll
    for (int nt = 0; nt < 3; ++nt) {
        ushort_t* basep = &Qst[(16 * nt + c) * KP];
        *(unsigned*)&basep[4 * g]          = Bf[nt][0].u[0];
        *(unsigned*)&basep[4 * g + 2]      = Bf[nt][0].u[1];
        *(unsigned*)&basep[16 + 4 * g]     = Bf[nt][0].u[2];
        *(unsigned*)&basep[16 + 4 * g + 2] = Bf[nt][0].u[3];
        *(unsigned*)&basep[32 + 4 * g]     = Bf[nt][1].u[0];
        *(unsigned*)&basep[32 + 4 * g + 2] = Bf[nt][1].u[1];
    }
    __syncthreads();

    if (lane < KK) {
        const int m = lane;
        unsigned w[24];
        #pragma unroll
        for (int np = 0; np < 24; ++np) {
            unsigned lo = Qst[(2 * np)     * KP + m];
            unsigned hi = Qst[(2 * np + 1) * KP + m];
            w[np] = (hi << 16) | lo;
        }
        ushort_t* dst = Qout + (size_t)job * (KK * KK) + m * KK;
        #pragma unroll
        for (int i4 = 0; i4 < 6; ++i4) {
            uint4 o; o.x = w[4*i4]; o.y = w[4*i4+1]; o.z = w[4*i4+2]; o.w = w[4*i4+3];
            *(uint4*)&dst[8 * i4] = o;
        }
    }
    if (lane == 0) sigout[job] = sg;
}

// ---------------- Kernel 2: per-batch combine + scores ----------------
template <int SEGT, int NSEGT>
__global__ __launch_bounds__(64) void crf_comb_kernel(
    const float* __restrict__ logits, const float* __restrict__ trans,
    const int* __restrict__ targets, const int* __restrict__ lens,
    const ushort_t* __restrict__ Qall, const float* __restrict__ sig,
    float* __restrict__ out)
{
    constexpr int NFULLT = NSEGT - 1;
    const int b = blockIdx.x, lane = threadIdx.x;
    const int jj = (lane < KK) ? lane : 0;
    const int L = lens[b];

    __shared__ float s_trans[KK * KK];
    for (int k = lane; k < KK * KK; k += 64) s_trans[k] = trans[k];
    __syncthreads();

    const float* lg_b = logits  + (size_t)b * TT * KK;
    const int*   tg_b = targets + (size_t)b * TT;

    float ub = 0.f;
    #pragma unroll 4
    for (int t = lane; t < TT; t += 64) {
        if (t < L) {
            int tg = tg_b[t];
            ub += lg_b[t * KK + tg];
            if (t >= 1) { int tp = tg_b[t - 1]; ub += s_trans[tp * KK + tg]; }
        }
    }
    #pragma unroll
    for (int d = 32; d >= 1; d >>= 1) ub += __shfl_xor(ub, d, 64);

    float log_norm = 0.f;
    if (L > 0) {
        float a0 = lg_b[jj];
        float M  = rlf(a0, 0);
        float s  = (lane < KK) ? __expf(a0 - M) : 0.f;
        int nf = (L >= 2) ? (L - 1) / SEGT : 0;
        if (nf > NFULLT) nf = NFULLT;

        for (int ci = 0; ci <= nf; ++ci) {           // full segments, then tail
            const int job = b * NSEGT + ((ci < nf) ? ci : NFULLT);
            const ushort_t* Qr = Qall + (size_t)job * (KK * KK) + jj * KK;
            unsigned rw[24];
            #pragma unroll
            for (int i4 = 0; i4 < 6; ++i4) {
                uint4 v = *(const uint4*)&Qr[8 * i4];
                rw[4*i4] = v.x; rw[4*i4+1] = v.y; rw[4*i4+2] = v.z; rw[4*i4+3] = v.w;
            }
            float acc = 0.f;
            #pragma unroll
            for (int ip = 0; ip < 24; ++ip) {
                unsigned u = rw[ip];
                float q0 = __uint_as_float(u << 16);
                float q1 = __uint_as_float(u & 0xFFFF0000u);
                acc = fmaf(rlf(s, 2 * ip),     q0, acc);
                acc = fmaf(rlf(s, 2 * ip + 1), q1, acc);
            }
            float r  = rlf(acc, 0);
            float rr = __builtin_amdgcn_rcpf(r);
            s = (lane < KK) ? acc * rr : 0.f;
            M += __logf(r) + sig[job];
        }

        float ssum = (lane < KK) ? s : 0.f;
        #pragma unroll
        for (int d = 32; d >= 1; d >>= 1) ssum += __shfl_xor(ssum, d, 64);
        log_norm = M + __logf(ssum);
    }

    if (lane == 0) out[b] = (L <= 0) ? 0.f : (ub - log_norm);
}

// ---------------- Round-3 fallback (ws too small) ----------------
__global__ __launch_bounds__(64) void crf_fwd_fallback(
    const float* __restrict__ logits, const float* __restrict__ trans,
    const int* __restrict__ targets, const int* __restrict__ lens,
    float* __restrict__ out)
{
    const int b = blockIdx.x, lane = threadIdx.x;
    const int jj = (lane < KK) ? lane : 0;
    const int L = lens[b];
    __shared__ float s_trans[KK * KK];
    for (int k = lane; k < KK * KK; k += 64) s_trans[k] = trans[k];
    float et[KK];
    #pragma unroll
    for (int i = 0; i < KK; ++i) et[i] = __expf(trans[i * KK + jj]);
    __syncthreads();
    const float* lg_b = logits + (size_t)b * TT * KK;
    const int* tg_b = targets + (size_t)b * TT;
    float ub = 0.f;
    for (int t = lane; t < TT; t += 64) {
        if (t < L) {
            int tg = tg_b[t];
            ub += lg_b[t * KK + tg];
            if (t >= 1) { int tp = tg_b[t - 1]; ub += s_trans[tp * KK + tg]; }
        }
    }
    #pragma unroll
    for (int d = 32; d >= 1; d >>= 1) ub += __shfl_xor(ub, d, 64);
    float a0 = lg_b[jj];
    float M = rlf(a0, 0);
    float s = (lane < KK) ? __expf(a0 - M) : 0.f;
    float sC = s, MC = M;
    const int Lm1 = L - 1;
    float pf[8];
    #pragma unroll
    for (int u = 0; u < 8; ++u) pf[u] = lg_b[(1 + u) * KK + jj];
    #pragma unroll 1
    for (int cc = 0; cc < 256; ++cc) {
        #pragma unroll
        for (int u = 0; u < 8; ++u) {
            const int t = 1 + cc * 8 + u;
            float lg = pf[u];
            int nrow = t + 8; if (nrow > TT - 1) nrow = TT - 1;
            pf[u] = lg_b[nrow * KK + jj];
            float eL = __expf(lg);
            float ac0 = 0.f, ac1 = 0.f, ac2 = 0.f, ac3 = 0.f;
            #pragma unroll
            for (int i = 0; i < KK; i += 4) {
                float s0 = rlf(s, i), s1 = rlf(s, i+1), s2 = rlf(s, i+2), s3 = rlf(s, i+3);
                ac0 = fmaf(s0, et[i], ac0);   ac1 = fmaf(s1, et[i+1], ac1);
                ac2 = fmaf(s2, et[i+2], ac2); ac3 = fmaf(s3, et[i+3], ac3);
            }
            float e = ((ac0 + ac1) + (ac2 + ac3)) * eL;
            bool cap = (t == Lm1);
            sC = cap ? e : sC;  MC = cap ? M : MC;
            float r = rlf(e, 0);
            s = e * __builtin_amdgcn_rcpf(r);
            M += __logf(r);
        }
    }
    float ssum = (lane < KK) ? sC : 0.f;
    #pragma unroll
    for (int d = 32; d >= 1; d >>= 1) ssum += __shfl_xor(ssum, d, 64);
    float log_norm = MC + __logf(ssum);
    if (lane == 0) out[b] = (L <= 0) ? 0.f : (ub - log_norm);
}

extern "C" void kernel_launch(void* const* d_in, const int* in_sizes, int n_in,
                              void* d_out, int out_size, void* d_ws, size_t ws_size,
                              hipStream_t stream) {
    const float* logits  = (const float*)d_in[0];
    const float* trans   = (const float*)d_in[1];
    const int*   targets = (const int*)  d_in[2];
    const int*   lens    = (const int*)  d_in[3];
    float*       out     = (float*)d_out;
    const int B = in_sizes[3];

    const size_t q64  = (size_t)B * 32 * KK * KK * sizeof(ushort_t);
    const size_t n64  = q64 + (size_t)B * 32 * sizeof(float);
    const size_t q128 = (size_t)B * 16 * KK * KK * sizeof(ushort_t);
    const size_t n128 = q128 + (size_t)B * 16 * sizeof(float);

    if (ws_size >= n64) {
        ushort_t* Qout = (ushort_t*)d_ws;
        float*    sig  = (float*)((char*)d_ws + q64);
        crf_seg_kernel<64, 32><<<dim3(B, 32), 64, 0, stream>>>(logits, trans, lens, Qout, sig);
        crf_comb_kernel<64, 32><<<B, 64, 0, stream>>>(logits, trans, targets, lens, Qout, sig, out);
    } else if (ws_size >= n128) {
        ushort_t* Qout = (ushort_t*)d_ws;
        float*    sig  = (float*)((char*)d_ws + q128);
        crf_seg_kernel<128, 16><<<dim3(B, 16), 64, 0, stream>>>(logits, trans, lens, Qout, sig);
        crf_comb_kernel<128, 16><<<B, 64, 0, stream>>>(logits, trans, targets, lens, Qout, sig, out);
    } else {
        crf_fwd_fallback<<<B, 64, 0, stream>>>(logits, trans, targets, lens, out);
    }
}